// Round 9
// baseline (396.747 us; speedup 1.0000x reference)
//
#include <hip/hip_runtime.h>
#include <stdint.h>

// Problem constants (fixed by the reference)
#define N_TOK 8192
#define IN_F 4096
#define OUT_F 4096
#define BS 256
#define ABPI 5
#define NFLAT 80          // 16 output blocks x 5 slots = all (g,a) pairs

typedef __attribute__((ext_vector_type(8))) short short8;    // 8 bf16 = 4 VGPRs (MFMA A/B frag)
typedef __attribute__((ext_vector_type(4))) float floatx4;   // MFMA C/D frag
typedef __attribute__((ext_vector_type(4))) unsigned short ushort4v;
typedef __attribute__((ext_vector_type(4))) unsigned int uint4v;

__device__ __forceinline__ unsigned short f2bf(float f) {
  union { float f; unsigned int u; } v; v.f = f;
  unsigned int r = v.u + 0x7FFFu + ((v.u >> 16) & 1u);   // RNE (bit-identical to old cvt_x)
  return (unsigned short)(r >> 16);
}

__device__ __forceinline__ void async16(const void* g, void* l) {
  __builtin_amdgcn_global_load_lds((const __attribute__((address_space(1))) void*)g,
                                   (__attribute__((address_space(3))) void*)l, 16, 0, 0);
}

// ---------------- kernel: weight fp32 -> bf16, transposed per (g,a) block ----
__global__ void cvt_w_kernel(const float* __restrict__ w, unsigned short* __restrict__ wt) {
  __shared__ unsigned short tile[64][68];
  int b = blockIdx.x;
  int fi = b >> 4;
  int t  = b & 15;
  int k0 = (t >> 2) * 64, o0 = (t & 3) * 64;
  int g = fi / ABPI, a = fi % ABPI;
  int tid = threadIdx.x;
  int tr = tid >> 4, tc = tid & 15;
  #pragma unroll
  for (int i = 0; i < 4; ++i) {
    int k = k0 + i * 16 + tr;
    const float* src = w + (size_t)(g * 256 + k) * (ABPI * BS) + a * BS + o0 + tc * 4;
    float4 v = *(const float4*)src;
    tile[tc * 4 + 0][i * 16 + tr] = f2bf(v.x);
    tile[tc * 4 + 1][i * 16 + tr] = f2bf(v.y);
    tile[tc * 4 + 2][i * 16 + tr] = f2bf(v.z);
    tile[tc * 4 + 3][i * 16 + tr] = f2bf(v.w);
  }
  __syncthreads();
  #pragma unroll
  for (int i = 0; i < 4; ++i) {
    int o = i * 16 + tr;
    unsigned short* dst = wt + (size_t)fi * (BS * BS) + (size_t)(o0 + o) * BS + k0 + tc * 4;
    *(ushort4v*)dst = *(const ushort4v*)&tile[o][tc * 4];
  }
}

// ---------------- fused butterfly block-sparse GEMM (A-cvt inlined) ------------
// 256x256 tile, 8 waves (2M x 4N), per-wave 128x64, BK=64, double-buffered LDS.
// A is staged REG-PATH from fp32 x: per window one 64-row quarter = 2 float4
// loads -> f2bf x8 -> 1 ds_write_b128 into the dead buffer (buf^1 holds t-1,
// fully consumed before tile-t entry barrier). Issue at window k, convert+write
// at window k+1 (T14): latency hides under MFMA. B staged via global_load_lds
// from pre-converted wt. End-of-tile: vmcnt(0) (B asyncs + any A loads) +
// lgkmcnt(0) (ds_writes) + barrier publishes tile t+1. Compiler auto-waits
// cover the reg-path A data deps.

#define BM 256
#define BN 256
#define BK 64
#define ABYTES 32768              // 256 rows x 128 B
#define BUFBYTES 65536            // A + B
#define SMEM_TOTAL 131072         // 2 buffers

#define SB() __builtin_amdgcn_sched_barrier(0)
#define PRIO1() __builtin_amdgcn_s_setprio(1)
#define PRIO0() __builtin_amdgcn_s_setprio(0)
#define BARRIER() __builtin_amdgcn_s_barrier()
#define LGKM0() do { asm volatile("s_waitcnt lgkmcnt(0)" ::: "memory"); SB(); } while (0)

__device__ __forceinline__ void ld_half_A(const char* p, int c0, int c1, short8 (&af)[4][2]) {
  #pragma unroll
  for (int mt = 0; mt < 4; ++mt) {
    const char* q = p + mt * 2048;
    af[mt][0] = *(const short8*)(q + c0);
    af[mt][1] = *(const short8*)(q + c1);
  }
}

__device__ __forceinline__ void ld_pair_B(const char* p, int c0, int c1, short8 (&bf)[2][2]) {
  #pragma unroll
  for (int nt = 0; nt < 2; ++nt) {
    const char* q = p + nt * 2048;
    bf[nt][0] = *(const short8*)(q + c0);
    bf[nt][1] = *(const short8*)(q + c1);
  }
}

__device__ __forceinline__ void mma16(const short8 (&af)[4][2], const short8 (&bf)[2][2],
                                      floatx4 (&acc)[8][4], int mb, int nb) {
  #pragma unroll
  for (int mt = 0; mt < 4; ++mt)
    #pragma unroll
    for (int nt = 0; nt < 2; ++nt) {
      acc[mb + mt][nb + nt] =
          __builtin_amdgcn_mfma_f32_16x16x32_bf16(af[mt][0], bf[nt][0], acc[mb + mt][nb + nt], 0, 0, 0);
      acc[mb + mt][nb + nt] =
          __builtin_amdgcn_mfma_f32_16x16x32_bf16(af[mt][1], bf[nt][1], acc[mb + mt][nb + nt], 0, 0, 0);
    }
}

// issue quarter q of next A tile (fp32, 8 floats/thread) into qa/qb
#define AQ_ISSUE(q, colA)                                                      \
  do { const float* p_ = xA + ((q) << 18) + (colA);                            \
       qa = *(const float4*)p_; qb = *(const float4*)(p_ + 4); } while (0)

// convert + write quarter q into the stage buffer (linear tid16 slot)
#define AQ_WRITE(q, Asd)                                                       \
  do { uint4v w_;                                                              \
       w_[0] = (unsigned)f2bf(qa.x) | ((unsigned)f2bf(qa.y) << 16);            \
       w_[1] = (unsigned)f2bf(qa.z) | ((unsigned)f2bf(qa.w) << 16);            \
       w_[2] = (unsigned)f2bf(qb.x) | ((unsigned)f2bf(qb.y) << 16);            \
       w_[3] = (unsigned)f2bf(qb.z) | ((unsigned)f2bf(qb.w) << 16);            \
       *(uint4v*)((Asd) + (q) * 8192 + tid16) = w_; } while (0)

// One K-tile; STAGE: stage tile t+1 (A from x at colA, B from wt at uB).
#define KTILE(Ab, Bb, Asd, Bsd, colA, uB, STAGE)                               \
  do {                                                                         \
    /* W1: A-quarter0 issue; reads A0+B01+B23; MFMA m0n01 */                   \
    if (STAGE) AQ_ISSUE(0, colA);                                              \
    ld_half_A((Ab) + rAb,        c0, c1, af);                                  \
    ld_pair_B((Bb) + rBb,        c0, c1, bf01);                                \
    ld_pair_B((Bb) + rBb + 4096, c0, c1, bf23);                                \
    SB(); BARRIER(); LGKM0();                                                  \
    PRIO1(); mma16(af, bf01, acc, 0, 0); PRIO0();                              \
    BARRIER();                                                                 \
    /* W2: write q0, issue q1 + B01 asyncs; MFMA m0n23 */                      \
    if (STAGE) { AQ_WRITE(0, Asd); AQ_ISSUE(1, colA);                          \
                 async16(pB0 + (uB), (Bsd)        + tid16);                    \
                 async16(pB1 + (uB), (Bsd) + 8192 + tid16); }                  \
    SB(); BARRIER();                                                           \
    PRIO1(); mma16(af, bf23, acc, 0, 2); PRIO0();                              \
    BARRIER();                                                                 \
    /* W3: write q1, issue q2 + B23 asyncs; reads A1; MFMA m1n23 */            \
    if (STAGE) { AQ_WRITE(1, Asd); AQ_ISSUE(2, colA);                          \
                 async16(pB2 + (uB), (Bsd) + 16384 + tid16);                   \
                 async16(pB3 + (uB), (Bsd) + 24576 + tid16); }                 \
    ld_half_A((Ab) + rAb + 8192, c0, c1, af);                                  \
    SB(); BARRIER(); LGKM0();                                                  \
    PRIO1(); mma16(af, bf23, acc, 4, 2); PRIO0();                              \
    BARRIER();                                                                 \
    /* W4: write q2, issue q3; MFMA m1n01; write q3; full drain + publish */   \
    if (STAGE) { AQ_WRITE(2, Asd); AQ_ISSUE(3, colA); }                        \
    SB(); BARRIER();                                                           \
    PRIO1(); mma16(af, bf01, acc, 4, 0); PRIO0();                              \
    if (STAGE) {                                                               \
      AQ_WRITE(3, Asd);                                                        \
      asm volatile("s_waitcnt vmcnt(0)" ::: "memory"); SB();                   \
      asm volatile("s_waitcnt lgkmcnt(0)" ::: "memory"); SB();                 \
      BARRIER();                                                               \
    }                                                                          \
  } while (0)

__global__ __launch_bounds__(512, 2)
void bfly_gemm(const float* __restrict__ x,             // [8192][4096] fp32
               const unsigned short* __restrict__ wt,   // [80][256 o][256 k] bf16
               const int* __restrict__ fidx,            // [16][5]
               float* __restrict__ out)                 // [8192][4096] fp32
{
  extern __shared__ __align__(16) char smem[];
  char* const b0A = smem;
  char* const b0B = b0A + ABYTES;
  char* const b1A = smem + BUFBYTES;
  char* const b1B = b1A + ABYTES;

  const int tid = threadIdx.x;
  // 512 blocks; bijective XCD swizzle (512 % 8 == 0)
  const int bx  = blockIdx.x;
  const int swz = (bx & 7) * 64 + (bx >> 3);
  const int ob  = swz >> 5;            // 0..15
  const int mt0 = swz & 31;            // 0..31
  const int m0  = mt0 * BM;
  const int n0g = ob * 256;

  int wbase[ABPI], gcol[ABPI];
  #pragma unroll
  for (int s = 0; s < ABPI; ++s) {
    int fi = __builtin_amdgcn_readfirstlane(fidx[ob * ABPI + s]);  // fi = g*5 + a
    wbase[s] = fi * (BS * BS);
    gcol[s]  = (fi / ABPI) * BS;       // column base in x (floats)
  }

  // staging constants: thread covers row sr (of 64) and 16B chunk sc; logical
  // chunk lc staged at physical slot sc with lc = sc ^ (sr&7) (0-conflict)
  const int sr = tid >> 3;
  const int sc = tid & 7;
  const int lc = sc ^ (sr & 7);
  const int tid16 = tid * 16;
  const float* xA = x + (size_t)(m0 + sr) * IN_F + lc * 8;   // + (q<<18) + colA
  const unsigned short* pB0 = wt + (  0 + sr) * BS + lc * 8;
  const unsigned short* pB1 = wt + ( 64 + sr) * BS + lc * 8;
  const unsigned short* pB2 = wt + (128 + sr) * BS + lc * 8;
  const unsigned short* pB3 = wt + (192 + sr) * BS + lc * 8;

  // fragment-read constants: 8 waves 2M x 4N; per-wave 128 m x 64 n
  const int lane = tid & 63;
  const int wv   = tid >> 6;
  const int wm   = (wv >> 2) * 128;    // 0 or 128
  const int wn   = (wv & 3) * 64;      // 0,64,128,192
  const int lrow = lane & 15;
  const int quad = lane >> 4;
  const int rAb  = (wm + lrow) * 128;  // byte; A row stride 128 B
  const int rBb  = (wn + lrow) * 128;
  const int c0   = ((quad)     ^ (lrow & 7)) * 16;
  const int c1   = c0 ^ 64;            // (quad+4)^r == (quad^r)^4 for quad<4

  short8 af[4][2], bf01[2][2], bf23[2][2];
  float4 qa, qb;                       // A-stage window (8 VGPR)
  floatx4 acc[8][4] = {};

  // ---- prologue: stage K-tile 0 fully into buf0, drain once ----
  {
    const int colA0 = gcol[0], uB0 = wbase[0];
    #pragma unroll
    for (int q = 0; q < 4; ++q) {
      AQ_ISSUE(q, colA0);
      AQ_WRITE(q, b0A);
    }
    async16(pB0 + uB0, b0B         + tid16);
    async16(pB1 + uB0, b0B +  8192 + tid16);
    async16(pB2 + uB0, b0B + 16384 + tid16);
    async16(pB3 + uB0, b0B + 24576 + tid16);
    asm volatile("s_waitcnt vmcnt(0)" ::: "memory"); SB();
    asm volatile("s_waitcnt lgkmcnt(0)" ::: "memory"); SB();
    BARRIER();
  }

  // ---- main loop: 20 K-tiles; tile t computes buf t&1, stages t+1 -> buf^1 --
  #pragma unroll 1
  for (int g = 0; g < 4; ++g) {
    const int wbg = wbase[g], gcg = gcol[g];
    const int wbn = wbase[g + 1], gcn = gcol[g + 1];
    KTILE(b0A, b0B, b1A, b1B, gcg +  64, wbg +  64, 1);
    KTILE(b1A, b1B, b0A, b0B, gcg + 128, wbg + 128, 1);
    KTILE(b0A, b0B, b1A, b1B, gcg + 192, wbg + 192, 1);
    KTILE(b1A, b1B, b0A, b0B, gcn,       wbn,       1);
  }
  { // group 4: tiles 16..19
    const int wbg = wbase[4], gcg = gcol[4];
    KTILE(b0A, b0B, b1A, b1B, gcg +  64, wbg +  64, 1);
    KTILE(b1A, b1B, b0A, b0B, gcg + 128, wbg + 128, 1);
    KTILE(b0A, b0B, b1A, b1B, gcg + 192, wbg + 192, 1);
    KTILE(b1A, b1B, b0A, b0B, 0,         0,         0);   // t=19: compute only
  }

  // ---- epilogue: C/D layout col=lane&15, row=quad*4+reg (m89-verified) ----
  #pragma unroll
  for (int m = 0; m < 8; ++m) {
    const int row = m0 + wm + (m >> 2) * 64 + (m & 3) * 16 + quad * 4;
    #pragma unroll
    for (int n = 0; n < 4; ++n) {
      const int col = n0g + wn + n * 16 + lrow;
      float* po = out + (size_t)row * OUT_F + col;
      #pragma unroll
      for (int r = 0; r < 4; ++r)
        po[(size_t)r * OUT_F] = acc[m][n][r];
    }
  }
}

extern "C" void kernel_launch(void* const* d_in, const int* in_sizes, int n_in,
                              void* d_out, int out_size, void* d_ws, size_t ws_size,
                              hipStream_t stream) {
  const float* x  = (const float*)d_in[0];          // [8192][4096]
  const float* w  = (const float*)d_in[1];          // [4096][5][256]
  const int* fidx = (const int*)d_in[2];            // [16][5]
  float* out = (float*)d_out;

  unsigned short* wt = (unsigned short*)d_ws;       // 10 MiB bf16 (xb eliminated)

  static int smem_set = 0;
  if (!smem_set) {
    hipFuncSetAttribute((const void*)bfly_gemm,
                        hipFuncAttributeMaxDynamicSharedMemorySize, SMEM_TOTAL);
    smem_set = 1;
  }

  cvt_w_kernel<<<NFLAT * 16, 256, 0, stream>>>(w, wt);
  bfly_gemm<<<16 * 32, 512, SMEM_TOTAL, stream>>>(x, wt, fidx, out);
}